// Round 1
// baseline (2493.347 us; speedup 1.0000x reference)
//
#include <hip/hip_runtime.h>
#include <cstdint>
#include <cstddef>

#define TN   8192
#define DD   512
#define NPER 4
#define KNN  5

// ---------------------------------------------------------------------------
// Sorted-5 insert (ascending by (val, idx) — matches stable argsort ties).
// All indices compile-time after unroll -> stays in registers (rule #20).
// ---------------------------------------------------------------------------
__device__ __forceinline__ void ins5(float v, int ix, float tv[KNN], int ti[KNN]) {
  if (v < tv[4] || (v == tv[4] && ix < ti[4])) {
    tv[4] = v; ti[4] = ix;
#pragma unroll
    for (int s = 4; s > 0; --s) {
      bool sw = (tv[s] < tv[s-1]) || (tv[s] == tv[s-1] && ti[s] < ti[s-1]);
      float nhi = sw ? tv[s-1] : tv[s];
      float nlo = sw ? tv[s]   : tv[s-1];
      int   ihi = sw ? ti[s-1] : ti[s];
      int   ilo = sw ? ti[s]   : ti[s-1];
      tv[s] = nhi; tv[s-1] = nlo;
      ti[s] = ihi; ti[s-1] = ilo;
    }
  }
}

// ---------------------------------------------------------------------------
// Kernel 1: rowsq[r] = sum_d X[r][d]^2   (one wave per row)
// ---------------------------------------------------------------------------
__global__ void sq_kernel(const float* __restrict__ X, float* __restrict__ rowsq) {
  const int row  = (int)blockIdx.x * 4 + ((int)threadIdx.x >> 6);
  const int lane = (int)threadIdx.x & 63;
  const float4* xr = (const float4*)(X + (size_t)row * DD);
  float4 a = xr[lane];
  float4 b = xr[lane + 64];
  float s = a.x*a.x + a.y*a.y + a.z*a.z + a.w*a.w
          + b.x*b.x + b.y*b.y + b.z*b.z + b.w*b.w;
#pragma unroll
  for (int off = 32; off >= 1; off >>= 1) s += __shfl_down(s, off, 64);
  if (lane == 0) rowsq[row] = s;
}

// ---------------------------------------------------------------------------
// Kernel 2: fused 64x4096 dot-tile + per-row running top-5 of
//           key = sq[j] - 2*dot(x_i, x_j)   (monotone in distance, j != i)
// Grid: 256 blocks = 128 row-blocks x 2 column halves. 512 threads (8 waves).
// Register tile 8 rows x 4 cols per thread; LDS double-buffered BK=16.
// LDS: A 2*16*68*4 = 8.5KB, B 2*16*260*4 = 33.3KB  (=> <64KB static, 8 w/CU)
// ---------------------------------------------------------------------------
#define ROW_FMA(q, as) \
  acc[q].x = fmaf(as, b.x, acc[q].x); \
  acc[q].y = fmaf(as, b.y, acc[q].y); \
  acc[q].z = fmaf(as, b.z, acc[q].z); \
  acc[q].w = fmaf(as, b.w, acc[q].w);

__launch_bounds__(512, 2)
__global__ void gemm_top5(const float* __restrict__ X, const float* __restrict__ rowsq,
                          float* __restrict__ topv, int* __restrict__ topi) {
  __shared__ float At[2][16][68];    // [buf][kk][row]  pad 68 -> aligned + few conflicts
  __shared__ float Bt[2][16][260];   // [buf][kk][col]  pad 260

  const int tid = (int)threadIdx.x;
  const int tx  = tid & 63;          // col group within wave
  const int ty  = tid >> 6;          // wave id = row group (broadcast A reads)
  const int bid = (int)blockIdx.x;
  const int rb  = bid >> 1;
  const int cb  = bid & 1;
  const int row0 = rb * 64;
  const int col0 = cb * 4096;

  const int ar = tid >> 2;           // A stage: row 0..63
  const int am = tid & 3;            // A stage: k-chunk 0..3

  float tv[8][KNN]; int ti[8][KNN];
#pragma unroll
  for (int q = 0; q < 8; ++q) {
#pragma unroll
    for (int s = 0; s < KNN; ++s) { tv[q][s] = 3.4e38f; ti[q][s] = 0x3fffffff; }
  }

  for (int ct = 0; ct < 16; ++ct) {        // column tiles of 256 within this half
    const int jb = col0 + ct * 256;

    float4 acc[8];
#pragma unroll
    for (int q = 0; q < 8; ++q) acc[q] = make_float4(0.f, 0.f, 0.f, 0.f);

    // pre-stage k-chunk 0 into buffer 0
    if (tid < 256) {
      float4 av = *(const float4*)(X + (size_t)(row0 + ar) * DD + am * 4);
      At[0][4*am+0][ar] = av.x; At[0][4*am+1][ar] = av.y;
      At[0][4*am+2][ar] = av.z; At[0][4*am+3][ar] = av.w;
    }
#pragma unroll
    for (int it = 0; it < 2; ++it) {
      int f = tid + it * 512;
      int j = f >> 2, m = f & 3;
      float4 bvv = *(const float4*)(X + (size_t)(jb + j) * DD + m * 4);
      Bt[0][4*m+0][j] = bvv.x; Bt[0][4*m+1][j] = bvv.y;
      Bt[0][4*m+2][j] = bvv.z; Bt[0][4*m+3][j] = bvv.w;
    }
    __syncthreads();

    for (int ks = 0; ks < 32; ++ks) {      // K = 512 in chunks of 16
      const int cur = ks & 1;
      const int nxt = cur ^ 1;
      const bool pf = (ks + 1) < 32;
      float4 av, bv0, bv1;
      if (pf) {                            // issue next-chunk loads early (G15)
        const int ko = (ks + 1) * 16;
        if (tid < 256)
          av = *(const float4*)(X + (size_t)(row0 + ar) * DD + ko + am * 4);
        { int j = tid >> 2, m = tid & 3;
          bv0 = *(const float4*)(X + (size_t)(jb + j) * DD + ko + m * 4); }
        { int f = tid + 512; int j = f >> 2, m = f & 3;
          bv1 = *(const float4*)(X + (size_t)(jb + j) * DD + ko + m * 4); }
      }

#pragma unroll
      for (int kk = 0; kk < 16; ++kk) {
        const float4 a0 = *(const float4*)&At[cur][kk][8*ty];
        const float4 a1 = *(const float4*)&At[cur][kk][8*ty+4];
        const float4 b  = *(const float4*)&Bt[cur][kk][4*tx];
        ROW_FMA(0, a0.x) ROW_FMA(1, a0.y) ROW_FMA(2, a0.z) ROW_FMA(3, a0.w)
        ROW_FMA(4, a1.x) ROW_FMA(5, a1.y) ROW_FMA(6, a1.z) ROW_FMA(7, a1.w)
      }

      if (pf) {                            // write next buffer (disjoint from cur)
        if (tid < 256) {
          At[nxt][4*am+0][ar] = av.x; At[nxt][4*am+1][ar] = av.y;
          At[nxt][4*am+2][ar] = av.z; At[nxt][4*am+3][ar] = av.w;
        }
        { int j = tid >> 2, m = tid & 3;
          Bt[nxt][4*m+0][j] = bv0.x; Bt[nxt][4*m+1][j] = bv0.y;
          Bt[nxt][4*m+2][j] = bv0.z; Bt[nxt][4*m+3][j] = bv0.w; }
        { int f = tid + 512; int j = f >> 2, m = f & 3;
          Bt[nxt][4*m+0][j] = bv1.x; Bt[nxt][4*m+1][j] = bv1.y;
          Bt[nxt][4*m+2][j] = bv1.z; Bt[nxt][4*m+3][j] = bv1.w; }
      }
      __syncthreads();
    }

    // epilogue: turn 32 dots into top-5 candidates
    const float4 sq4 = *(const float4*)(rowsq + jb + 4 * tx);
#pragma unroll
    for (int q = 0; q < 8; ++q) {
      const int gi = row0 + 8 * ty + q;
      const int j0 = jb + 4 * tx;
      float key;
      key = fmaf(-2.f, acc[q].x, sq4.x); if (j0+0 != gi) ins5(key, j0+0, tv[q], ti[q]);
      key = fmaf(-2.f, acc[q].y, sq4.y); if (j0+1 != gi) ins5(key, j0+1, tv[q], ti[q]);
      key = fmaf(-2.f, acc[q].z, sq4.z); if (j0+2 != gi) ins5(key, j0+2, tv[q], ti[q]);
      key = fmaf(-2.f, acc[q].w, sq4.w); if (j0+3 != gi) ins5(key, j0+3, tv[q], ti[q]);
    }
  }

  // butterfly merge across the 64 lanes of this wave (each wave owns 8 rows)
#pragma unroll
  for (int d = 1; d < 64; d <<= 1) {
#pragma unroll
    for (int q = 0; q < 8; ++q) {
      float ov[KNN]; int oi[KNN];
#pragma unroll
      for (int s = 0; s < KNN; ++s) {      // snapshot BEFORE mutating
        ov[s] = __shfl_xor(tv[q][s], d, 64);
        oi[s] = __shfl_xor(ti[q][s], d, 64);
      }
#pragma unroll
      for (int s = 0; s < KNN; ++s) ins5(ov[s], oi[s], tv[q], ti[q]);
    }
  }

  if (tx == 0) {
#pragma unroll
    for (int q = 0; q < 8; ++q) {
      const int gi = row0 + 8 * ty + q;
#pragma unroll
      for (int s = 0; s < KNN; ++s) {
        topv[(gi * 2 + cb) * KNN + s] = tv[q][s];
        topi[(gi * 2 + cb) * KNN + s] = ti[q][s];
      }
    }
  }
}

// ---------------------------------------------------------------------------
// Kernel 3: merge the two column-half top-5 lists -> final nn[T][5] (sorted)
// ---------------------------------------------------------------------------
__global__ void merge_nn(const float* __restrict__ topv, const int* __restrict__ topi,
                         int* __restrict__ nn) {
  const int i = (int)blockIdx.x * 256 + (int)threadIdx.x;
  float tv[KNN]; int ti[KNN];
#pragma unroll
  for (int s = 0; s < KNN; ++s) { tv[s] = topv[(i*2+0)*KNN + s]; ti[s] = topi[(i*2+0)*KNN + s]; }
#pragma unroll
  for (int s = 0; s < KNN; ++s) ins5(topv[(i*2+1)*KNN + s], topi[(i*2+1)*KNN + s], tv, ti);
#pragma unroll
  for (int s = 0; s < KNN; ++s) nn[i*KNN + s] = ti[s];
}

// ---------------------------------------------------------------------------
// Kernel 4: synthesis  out[i*4+p] = x_i + g * (x_nn - x_i)
// ---------------------------------------------------------------------------
__global__ void synth_kernel(const float* __restrict__ X, const int* __restrict__ nn,
                             const float* __restrict__ gaps, const int* __restrict__ choice,
                             float* __restrict__ out) {
  const float4* X4 = (const float4*)X;
  float4* O4 = (float4*)out;
  const int base = (int)blockIdx.x * 256 + (int)threadIdx.x;
#pragma unroll
  for (int it = 0; it < 8; ++it) {
    const int f    = base + it * (2048 * 256);
    const int orow = f >> 7;            // output row (= i*NPER + p)
    const int d4   = f & 127;           // float4 within row
    const int i    = orow >> 2;
    const int ch   = choice[orow];
    const int nr   = nn[i * KNN + ch];
    const float g  = gaps[orow];
    const float4 xi = X4[(size_t)i  * 128 + d4];
    const float4 xn = X4[(size_t)nr * 128 + d4];
    float4 r;
    r.x = fmaf(g, xn.x - xi.x, xi.x);
    r.y = fmaf(g, xn.y - xi.y, xi.y);
    r.z = fmaf(g, xn.z - xi.z, xi.z);
    r.w = fmaf(g, xn.w - xi.w, xi.w);
    O4[(size_t)orow * 128 + d4] = r;
  }
}

// ---------------------------------------------------------------------------
extern "C" void kernel_launch(void* const* d_in, const int* in_sizes, int n_in,
                              void* d_out, int out_size, void* d_ws, size_t ws_size,
                              hipStream_t stream) {
  const float* X      = (const float*)d_in[0];   // [8192, 512] fp32
  const float* gaps   = (const float*)d_in[1];   // [8192, 4]  fp32
  const int*   choice = (const int*)  d_in[2];   // [8192, 4]  int32 (values 0..4)
  float* out = (float*)d_out;

  // workspace layout (fp32 elems): sq[8192] | topv[8192*2*5] | topi | nn  (~852 KB)
  float* rowsq = (float*)d_ws;
  float* topv  = rowsq + TN;
  int*   topi  = (int*)(topv + (size_t)TN * 2 * KNN);
  int*   nn    = (int*)(topi + (size_t)TN * 2 * KNN);

  sq_kernel  <<<TN / 4,  256, 0, stream>>>(X, rowsq);
  gemm_top5  <<<256,     512, 0, stream>>>(X, rowsq, topv, topi);
  merge_nn   <<<TN / 256,256, 0, stream>>>(topv, topi, nn);
  synth_kernel<<<2048,   256, 0, stream>>>(X, nn, gaps, choice, out);
}